// Round 1
// baseline (63655.548 us; speedup 1.0000x reference)
//
#include <hip/hip_runtime.h>
#include <cstdint>

#define T_STEPS 8192
#define HDIM    768
#define G3      2304   // 3*H
#define NDR     4608   // 2*3*H
#define HC      1536   // 2*H
#define RPW     4      // h-rows per wave
#define WPD     192    // waves per direction = 768/RPW
#define NWAVE   384    // 2 dirs x 192 waves (independent cliques)

// ---------------------------------------------------------------------------
// GEMM: C[m][n] = sum_k X[m][k] * W[n][k] + bias[n]
// X: [M,K] row-major, W: [N,K] row-major. 128x128 tile, BK=16, 256 thr, 8x8.
// (unchanged from previous round — not the bottleneck)
// ---------------------------------------------------------------------------
__global__ __launch_bounds__(256)
void gemm_xwt(const float* __restrict__ X, const float* __restrict__ W,
              const float* __restrict__ bias, float* __restrict__ C,
              int M, int N, int K) {
    __shared__ float As[16][132];
    __shared__ float Bs[16][132];
    const int tid = threadIdx.x;
    const int m0 = blockIdx.y * 128;
    const int n0 = blockIdx.x * 128;
    const int tm = tid >> 4;
    const int tn = tid & 15;
    float acc[8][8] = {};
    for (int k0 = 0; k0 < K; k0 += 16) {
        #pragma unroll
        for (int l = 0; l < 2; ++l) {
            int idx = l * 256 + tid;
            int row = idx >> 2;
            int kc  = (idx & 3) << 2;
            float4 a = *(const float4*)(X + (size_t)(m0 + row) * K + k0 + kc);
            As[kc + 0][row] = a.x; As[kc + 1][row] = a.y;
            As[kc + 2][row] = a.z; As[kc + 3][row] = a.w;
            float4 b = *(const float4*)(W + (size_t)(n0 + row) * K + k0 + kc);
            Bs[kc + 0][row] = b.x; Bs[kc + 1][row] = b.y;
            Bs[kc + 2][row] = b.z; Bs[kc + 3][row] = b.w;
        }
        __syncthreads();
        #pragma unroll
        for (int k = 0; k < 16; ++k) {
            float4 a0 = *(const float4*)&As[k][tm * 8];
            float4 a1 = *(const float4*)&As[k][tm * 8 + 4];
            float4 b0 = *(const float4*)&Bs[k][tn * 8];
            float4 b1 = *(const float4*)&Bs[k][tn * 8 + 4];
            float av[8] = {a0.x, a0.y, a0.z, a0.w, a1.x, a1.y, a1.z, a1.w};
            float bv[8] = {b0.x, b0.y, b0.z, b0.w, b1.x, b1.y, b1.z, b1.w};
            #pragma unroll
            for (int i = 0; i < 8; ++i)
                #pragma unroll
                for (int j = 0; j < 8; ++j)
                    acc[i][j] = fmaf(av[i], bv[j], acc[i][j]);
        }
        __syncthreads();
    }
    float bfrag[8];
    #pragma unroll
    for (int j = 0; j < 8; ++j) bfrag[j] = bias[n0 + tn * 8 + j];
    #pragma unroll
    for (int i = 0; i < 8; ++i) {
        float* cp = C + (size_t)(m0 + tm * 8 + i) * N + n0 + tn * 8;
        float4 o0, o1;
        o0.x = acc[i][0] + bfrag[0]; o0.y = acc[i][1] + bfrag[1];
        o0.z = acc[i][2] + bfrag[2]; o0.w = acc[i][3] + bfrag[3];
        o1.x = acc[i][4] + bfrag[4]; o1.y = acc[i][5] + bfrag[5];
        o1.z = acc[i][6] + bfrag[6]; o1.w = acc[i][7] + bfrag[7];
        *(float4*)(cp + 0) = o0;
        *(float4*)(cp + 4) = o1;
    }
}

// ---------------------------------------------------------------------------
// GRU recurrence, R10: fully wave-autonomous — ZERO __syncthreads, ZERO LDS.
// 384 single-wave blocks = 2 cliques of 192. Each wave owns RPW=4 rows
// (all 3 gates = 12 dots of 768, weights register-resident, 144 VGPR).
// Per step: every lane polls the 12 tagged h-pairs it consumes (indices
// i*256+lane*4+k) straight into registers -> 144 FMA -> 6-stage butterfly
// (all 12 sums broadcast to all lanes) -> lanes 0..3 compute one row's
// gates each IN PARALLEL -> publish 4 contiguous 8-B pairs + Hout.
// Removes from the per-step critical chain: both barriers, hsh write/read,
// gsum round trip (and all LDS bank conflicts), serial 8-row gate compute.
// Overwrite safety (2-deep parity exchange) unchanged: lane-0..3's published
// value data-depends via the butterfly on every lane's polled reads, so
// read(t) precedes publish(t+1) per wave; the standard induction follows.
// Dot partition / butterfly order identical to R9 -> identical numerics.
// ---------------------------------------------------------------------------
__device__ __forceinline__ float sigf(float x) {
    return 1.0f / (1.0f + expf(-x));
}
__device__ __forceinline__ unsigned long long ld_pair(
        const unsigned long long* p) {
    return __hip_atomic_load(p, __ATOMIC_RELAXED, __HIP_MEMORY_SCOPE_AGENT);
}
__device__ __forceinline__ void st_pair(unsigned long long* p,
                                        unsigned long long v) {
    __hip_atomic_store(p, v, __ATOMIC_RELAXED, __HIP_MEMORY_SCOPE_AGENT);
}

__global__ __launch_bounds__(64, 1)
void gru_rec(const float* __restrict__ Gi,   // [T][2][2304]
             const float* __restrict__ whh,  // [2][2304][768]
             const float* __restrict__ bhh,  // [2][2304]
             const float* __restrict__ h0,   // [2][768] (layer slice)
             unsigned long long* __restrict__ exch, // [2 par][2 dir][768]
             float* __restrict__ Hout) {     // [T][2][768]
    const int lane = threadIdx.x;
    const int wid  = blockIdx.x;
    const int d    = wid / WPD;
    const int j0   = (wid % WPD) * RPW;

    // Register-resident weights: m = g*4 + r -> gate g, row j0+r.
    // w[m][i] covers h elements i*256 + lane*4 .. +3 (same partition as R9).
    float4 w[12][3];
    #pragma unroll
    for (int g = 0; g < 3; ++g)
        #pragma unroll
        for (int r = 0; r < RPW; ++r) {
            const float* wrow = whh + (size_t)d * G3 * HDIM
                + (size_t)(g * 768 + j0 + r) * HDIM;
            #pragma unroll
            for (int i = 0; i < 3; ++i)
                w[g * RPW + r][i] = *(const float4*)(wrow + i * 256 + lane * 4);
        }

    // Gate lanes (lane<4): row = j0 + lane; constants + initial h.
    float bh_r = 0.f, bh_z = 0.f, bh_n = 0.f, hprev = 0.f;
    if (lane < RPW) {
        const int row = j0 + lane;
        bh_r  = bhh[d * G3 +        row];
        bh_z  = bhh[d * G3 +  768 + row];
        bh_n  = bhh[d * G3 + 1536 + row];
        hprev = h0[d * 768 + row];
    }

    // Gi prefetch, one step ahead (double-buffered in registers).
    float gi_r = 0.f, gi_z = 0.f, gi_n = 0.f;
    if (lane < RPW) {
        const float* gp = Gi + (size_t)d * G3;
        gi_r = gp[        j0 + lane];
        gi_z = gp[ 768 + j0 + lane];
        gi_n = gp[1536 + j0 + lane];
    }

    for (int t = 0; t < T_STEPS; ++t) {
        // Issue next step's Gi loads now; consumed next iteration (HBM
        // latency hides under this step's poll + compute).
        float ngr = 0.f, ngz = 0.f, ngn = 0.f;
        if (lane < RPW && t + 1 < T_STEPS) {
            const float* gp = Gi + ((size_t)(t + 1) * 2 + d) * G3;
            ngr = gp[        j0 + lane];
            ngz = gp[ 768 + j0 + lane];
            ngn = gp[1536 + j0 + lane];
        }

        // --- per-lane direct poll of the 12 consumed h values ---
        float4 h4[3];
        if (t == 0) {
            const float* src = h0 + d * 768;
            #pragma unroll
            for (int i = 0; i < 3; ++i)
                h4[i] = *(const float4*)(src + i * 256 + lane * 4);
        } else {
            const unsigned long long* src = exch
                + (size_t)((((t - 1) & 1) * 2 + d)) * 768 + lane * 4;
            unsigned long long v[12];
            bool ok;
            do {
                #pragma unroll
                for (int i = 0; i < 3; ++i)
                    #pragma unroll
                    for (int k = 0; k < 4; ++k)
                        v[i * 4 + k] = ld_pair(src + i * 256 + k);
                ok = true;
                #pragma unroll
                for (int m = 0; m < 12; ++m)
                    ok &= ((unsigned)v[m] >= (unsigned)t);
                if (!ok) __builtin_amdgcn_s_sleep(1);  // ease the poll storm
            } while (!ok);
            #pragma unroll
            for (int i = 0; i < 3; ++i) {
                float* hp = (float*)&h4[i];
                #pragma unroll
                for (int k = 0; k < 4; ++k)
                    hp[k] = __uint_as_float((unsigned)(v[i * 4 + k] >> 32));
            }
        }

        // --- 12 dots (144 FMA/lane) straight from polled registers ---
        float S[12];
        #pragma unroll
        for (int m = 0; m < 12; ++m) {
            float s = 0.f;
            s = fmaf(w[m][0].x, h4[0].x, s); s = fmaf(w[m][0].y, h4[0].y, s);
            s = fmaf(w[m][0].z, h4[0].z, s); s = fmaf(w[m][0].w, h4[0].w, s);
            s = fmaf(w[m][1].x, h4[1].x, s); s = fmaf(w[m][1].y, h4[1].y, s);
            s = fmaf(w[m][1].z, h4[1].z, s); s = fmaf(w[m][1].w, h4[1].w, s);
            s = fmaf(w[m][2].x, h4[2].x, s); s = fmaf(w[m][2].y, h4[2].y, s);
            s = fmaf(w[m][2].z, h4[2].z, s); s = fmaf(w[m][2].w, h4[2].w, s);
            S[m] = s;
        }
        #pragma unroll
        for (int sft = 1; sft < 64; sft <<= 1) {
            #pragma unroll
            for (int m = 0; m < 12; ++m) S[m] += __shfl_xor(S[m], sft);
        }

        // --- gates, 4 rows in parallel on lanes 0..3, then publish ---
        if (lane < RPW) {
            // static-index select of this lane's 3 sums (avoid scratch)
            float Sr = (lane & 2) ? ((lane & 1) ? S[3]  : S[2])
                                  : ((lane & 1) ? S[1]  : S[0]);
            float Sz = (lane & 2) ? ((lane & 1) ? S[7]  : S[6])
                                  : ((lane & 1) ? S[5]  : S[4]);
            float Sn = (lane & 2) ? ((lane & 1) ? S[11] : S[10])
                                  : ((lane & 1) ? S[9]  : S[8]);
            float r = sigf(gi_r + Sr + bh_r);
            float z = sigf(gi_z + Sz + bh_z);
            float n = tanhf(gi_n + r * (Sn + bh_n));
            float hn = (1.0f - z) * n + z * hprev;
            hprev = hn;
            unsigned long long pair =
                ((unsigned long long)__float_as_uint(hn) << 32)
                | (unsigned long long)(unsigned)(t + 1);
            st_pair(exch + (size_t)(((t & 1) * 2 + d)) * 768 + j0 + lane, pair);
            Hout[((size_t)t * 2 + d) * 768 + j0 + lane] = hn;
        }
        gi_r = ngr; gi_z = ngz; gi_n = ngn;
    }
}

// ---------------------------------------------------------------------------
// Final FC + sigmoid: out[r] = sigmoid(fc_w[r] . hin + fc_b[r]); one wave/row.
// ---------------------------------------------------------------------------
__device__ __forceinline__ float dot4(float4 a, float4 b) {
    return a.x * b.x + a.y * b.y + a.z * b.z + a.w * b.w;
}

__global__ __launch_bounds__(64)
void fc_sig(const float* __restrict__ hin, const float* __restrict__ fw,
            const float* __restrict__ fb, float* __restrict__ out) {
    const int lane = threadIdx.x;
    const int row  = blockIdx.x;
    const float* wr = fw + (size_t)row * HC;
    float acc = 0.0f;
    #pragma unroll
    for (int i = 0; i < 6; ++i) {
        float4 w4 = *(const float4*)(wr  + i * 256 + lane * 4);
        float4 h4 = *(const float4*)(hin + i * 256 + lane * 4);
        acc += dot4(w4, h4);
    }
    #pragma unroll
    for (int s = 1; s < 64; s <<= 1) acc += __shfl_xor(acc, s);
    if (lane == 0) out[row] = sigf(acc + fb[row]);
}

// ---------------------------------------------------------------------------
extern "C" void kernel_launch(void* const* d_in, const int* in_sizes, int n_in,
                              void* d_out, int out_size, void* d_ws, size_t ws_size,
                              hipStream_t stream) {
    (void)in_sizes; (void)n_in; (void)out_size; (void)ws_size;

    const float* x     = (const float*)d_in[0];   // [8192,512]
    const float* h0    = (const float*)d_in[1];   // [4,768]
    const float* w_ih0 = (const float*)d_in[2];   // [2,2304,512]
    const float* w_hh0 = (const float*)d_in[3];   // [2,2304,768]
    const float* b_ih0 = (const float*)d_in[4];   // [2,2304]
    const float* b_hh0 = (const float*)d_in[5];
    const float* w_ih1 = (const float*)d_in[6];   // [2,2304,1536]
    const float* w_hh1 = (const float*)d_in[7];
    const float* b_ih1 = (const float*)d_in[8];
    const float* b_hh1 = (const float*)d_in[9];
    const float* fc_w  = (const float*)d_in[10];  // [256,1536]
    const float* fc_b  = (const float*)d_in[11];  // [256]
    float* out = (float*)d_out;

    char* ws = (char*)d_ws;
    // Exchange pair buffers (tags must start 0): 2*2*768*8 B = 24 KiB each.
    unsigned long long* exch0 = (unsigned long long*)(ws + 4096);
    unsigned long long* exch1 = (unsigned long long*)(ws + 4096 + 24576);
    float* Gi    = (float*)(ws + 65536);           // [8192][4608] fp32 = 144 MiB
    size_t gi_bytes = (size_t)T_STEPS * NDR * sizeof(float);
    float* Hout  = (float*)(ws + 65536 + gi_bytes); // [8192][2][768] = 48 MiB

    hipMemsetAsync(ws, 0, 65536, stream);

    dim3 ggrid(NDR / 128, T_STEPS / 128);  // (36, 64)

    // Phase 1: Gi0 = x @ w_ih0^T + b_ih0
    gemm_xwt<<<ggrid, 256, 0, stream>>>(x, w_ih0, b_ih0, Gi, T_STEPS, NDR, 512);
    // Phase 2: layer-0 recurrence, store all h0[t]
    gru_rec<<<NWAVE, 64, 0, stream>>>(Gi, w_hh0, b_hh0, h0, exch0, Hout);
    // Phase 3: Gi1 = concat_h0 @ w_ih1^T + b_ih1
    gemm_xwt<<<ggrid, 256, 0, stream>>>(Hout, w_ih1, b_ih1, Gi, T_STEPS, NDR, HC);
    // Phase 4: layer-1 recurrence
    gru_rec<<<NWAVE, 64, 0, stream>>>(Gi, w_hh1, b_hh1, h0 + 2 * HDIM, exch1, Hout);
    // Phase 5: y = sigmoid(fc_w @ h_last + fc_b)
    fc_sig<<<256, 64, 0, stream>>>(Hout + (size_t)(T_STEPS - 1) * HC,
                                   fc_w, fc_b, out);
}